// Round 11
// baseline (62.441 us; speedup 1.0000x reference)
//
#include <hip/hip_runtime.h>
#include <hip/hip_bf16.h>
#include <stdint.h>

#define H_NUM 16
#define S_LEN 2048
#define D_DIM 128
#define WIN   512
#define HSD   (H_NUM * S_LEN * D_DIM)   // 4194304 elements
#define VSTRIDE (S_LEN + 8)             // padded Vt row stride (r4 fix)
#define NWG   256                       // 16 heads x 16 q-groups(128 rows)
#define REP   2                         // measurement round: loop main flash 2x

typedef __attribute__((ext_vector_type(8)))  _Float16 half8;
typedef __attribute__((ext_vector_type(4)))  _Float16 half4;
typedef __attribute__((ext_vector_type(2)))  __fp16   fp16x2;
typedef __attribute__((ext_vector_type(4)))  float f32x4;
typedef __attribute__((ext_vector_type(16))) float f32x16;
typedef __attribute__((ext_vector_type(4)))  unsigned int uint4v;

static __device__ __forceinline__ void gload16(const void* g, void* l) {
    __builtin_amdgcn_global_load_lds(
        (const __attribute__((address_space(1))) uint32_t*)g,
        (__attribute__((address_space(3))) uint32_t*)l, 16, 0, 0);
}
static __device__ __forceinline__ uint32_t pk16(float a, float b) {
    fp16x2 t = __builtin_amdgcn_cvt_pkrtz(a, b);   // v_cvt_pkrtz_f16_f32
    return __builtin_bit_cast(uint32_t, t);
}

// ---- fused pre-pass: K fp32->fp16 (streaming) + V transpose (32x32 fp32 tile,
// conflict-free: read t[c+e][r] banks = (c+r+const)%32, <=3-way) ----
__global__ __launch_bounds__(256) void prep(
    const float* __restrict__ K, const float* __restrict__ V,
    _Float16* __restrict__ kf, _Float16* __restrict__ vt)
{
    __shared__ float t[32][33];
    int h = blockIdx.z, s0 = blockIdx.x * 32, d0 = blockIdx.y * 32;
    int tid = threadIdx.x;

    // K convert: this block's linear 1024-elem chunk
    size_t blk = ((size_t)blockIdx.z * gridDim.y + blockIdx.y) * gridDim.x + blockIdx.x;
    size_t ki = (blk * 256 + tid) * 4;
    float4 kx = *reinterpret_cast<const float4*>(K + ki);
    half4 kh4 = {(_Float16)kx.x, (_Float16)kx.y, (_Float16)kx.z, (_Float16)kx.w};
    *reinterpret_cast<half4*>(kf + ki) = kh4;

    // V transpose tile
    int r = tid >> 3;          // 0..31
    int c = (tid & 7) * 4;     // 0,4,...,28
    float4 x = *reinterpret_cast<const float4*>(
        V + ((size_t)(h * S_LEN + s0 + r) << 7) + d0 + c);
    t[r][c + 0] = x.x; t[r][c + 1] = x.y; t[r][c + 2] = x.z; t[r][c + 3] = x.w;
    __syncthreads();
    half4 y;
    #pragma unroll
    for (int e = 0; e < 4; ++e) y[e] = (_Float16)t[c + e][r];
    *reinterpret_cast<half4*>(vt + (size_t)(h * D_DIM + d0 + r) * VSTRIDE + s0 + c) = y;
}

// ---- main: 8 waves/WG = 4 q-tiles(32) x 2 window-halves; 32x32 MFMA ----
// mfma_f32_32x32x16_f16: A row=lane&31,k=(lane>>5)*8+e; B col=lane&31,same k;
// C/D col=lane&31, row=(reg&3)+8*(reg>>2)+4*(lane>>5).
// REP=2 measurement loop: recompute flash pass twice, store once.
__global__ __launch_bounds__(512, 2) void swa_fwd(
    const float* __restrict__ Q, const _Float16* __restrict__ kf,
    const _Float16* __restrict__ vt, float* __restrict__ O)
{
    __shared__ __align__(16) char arena[71680];
    char* ksL = arena;                          // [2][8192] K low
    char* vsL = arena + 16384;                  // [2][8192] V low
    char* ksH = arena + 32768;                  // [2][8192] K high
    char* vsH = arena + 49152;                  // [2][8192] V high
    float* mrg_o  = (float*)arena;              // [4][64][68] (post-loop alias)
    float* mrg_ml = (float*)(arena + 69632);    // [4][64][2]

    int bid = blockIdx.x;
    int wid = ((bid & 7) << 5) | (bid >> 3);    // XCD-bijective (256%8==0)
    int h    = wid >> 4;
    int q0wg = (wid & 15) << 7;

    int tid  = threadIdx.x;
    int wv   = tid >> 6;
    int lane = tid & 63;
    int qn = lane & 31;
    int hi = lane >> 5;
    int qsel = wv & 3;
    int hseg = wv >> 2;
    int q0 = q0wg + qsel * 32;

    const float*    Qh = Q  + ((size_t)h << 18);
    const char*     Kb = (const char*)(kf + ((size_t)h << 18));
    const char*     Vb = (const char*)(vt + (size_t)h * D_DIM * VSTRIDE);
    float*          Oh = O  + ((size_t)h << 18);

    half8 qa[8];
    const float* qrow = Qh + ((size_t)(q0 + qn) << 7) + hi * 8;
    #pragma unroll
    for (int c = 0; c < 8; ++c) {
        float4 a0 = *reinterpret_cast<const float4*>(qrow + c * 16);
        float4 a1 = *reinterpret_cast<const float4*>(qrow + c * 16 + 4);
        qa[c] = (half8){(_Float16)a0.x, (_Float16)a0.y, (_Float16)a0.z, (_Float16)a0.w,
                        (_Float16)a1.x, (_Float16)a1.y, (_Float16)a1.z, (_Float16)a1.w};
    }

    int kstart = q0wg - (WIN - 1);
    if (kstart < 0) kstart = 0;
    kstart &= ~31;
    int nt  = ((q0wg + 128) - kstart) >> 5;
    int nt0 = (nt + 1) >> 1;
    int ntH = nt - nt0;                  // >= 1
    int iq   = q0 + qn;
    int w_ks = q0 - (WIN - 1);
    int w_ke = q0 + 32;

#define STAGE1(KS, VS, BUF, KB_) do {                                            \
        int sb_ = wv * 1024 + lane * 16;                                         \
        int kr_ = sb_ >> 8;                                                      \
        int kc_ = (sb_ & 255) ^ ((kr_ & 7) << 4);                                \
        gload16(Kb + (((size_t)((KB_) + kr_)) << 8) + kc_,                       \
                (KS) + (BUF) * 8192 + wv * 1024);                                \
        int vs_ = sb_ >> 11;                                                     \
        int vd_ = (sb_ >> 4) & 127;                                              \
        gload16(Vb + (size_t)vd_ * (VSTRIDE * 2) + (size_t)((KB_) + vs_ * 8) * 2,\
                (VS) + (BUF) * 8192 + wv * 1024);                                \
    } while (0)

    f32x16 oacc[4];
    float m_s, l_s;
    int my_cnt = hseg ? ntH : nt0;

    for (int rep = 0; rep < REP; ++rep) {
        #pragma unroll
        for (int db = 0; db < 4; ++db)
            #pragma unroll
            for (int i = 0; i < 16; ++i) oacc[db][i] = 0.f;
        m_s = -1e30f; l_s = 0.f;

        STAGE1(ksL, vsL, 0, kstart);
        STAGE1(ksH, vsH, 0, kstart + nt0 * 32);

        for (int it = 0; it < nt0; ++it) {
            int cur = it & 1;
            int nxt = cur ^ 1;
            int pfL = (it + 1 < nt0) ? it + 1 : nt0 - 1;   // clamped dummy keeps
            int pfH = (it + 1 < ntH) ? it + 1 : ntH - 1;   // vmcnt uniform (4/iter)
            STAGE1(ksL, vsL, nxt, kstart + pfL * 32);
            STAGE1(ksH, vsH, nxt, kstart + (nt0 + pfH) * 32);

            asm volatile("s_waitcnt vmcnt(4)" ::: "memory");
            __builtin_amdgcn_s_barrier();
            __builtin_amdgcn_sched_barrier(0);

            int mt = (hseg ? nt0 : 0) + it;
            int kb = kstart + mt * 32;
            bool act = (it < my_cnt) && (kb < w_ke) && (kb + 32 > w_ks);
            if (act) {
                const char* ksb = (hseg ? ksH : ksL) + cur * 8192;
                const char* vsb = (hseg ? vsH : vsL) + cur * 8192;

                // QK^T swapped: D[key][q]
                f32x16 sacc;
                #pragma unroll
                for (int i = 0; i < 16; ++i) sacc[i] = 0.f;
                int sw = (qn & 7) << 4;
                #pragma unroll
                for (int c = 0; c < 8; ++c) {
                    half8 kh = *reinterpret_cast<const half8*>(
                        ksb + qn * 256 + ((c * 32 + hi * 16) ^ sw));
                    sacc = __builtin_amdgcn_mfma_f32_32x32x16_f16(kh, qa[c], sacc, 0, 0, 0);
                }

                // mask (interior skip) + 16-wide softmax
                float p[16];
                bool fullt = (kb >= q0 - 480) && (kb <= q0 - 31);
                if (fullt) {
                    #pragma unroll
                    for (int r = 0; r < 16; ++r) p[r] = sacc[r];
                } else {
                    #pragma unroll
                    for (int r = 0; r < 16; ++r) {
                        int j = kb + (r & 3) + 8 * (r >> 2) + 4 * hi;
                        p[r] = ((j <= iq) && (j + WIN > iq)) ? sacc[r] : -1e30f;
                    }
                }
                float tm = p[0];
                #pragma unroll
                for (int r = 1; r < 16; ++r) tm = fmaxf(tm, p[r]);
                tm = fmaxf(tm, __shfl_xor(tm, 32));

                if (!__all(tm - m_s <= 8.f)) {       // T13 defer-max
                    float mn = fmaxf(m_s, tm);
                    float scale = __expf(m_s - mn);  // 0 wipes fresh-lane junk
                    m_s = mn;
                    l_s *= scale;
                    #pragma unroll
                    for (int r = 0; r < 16; ++r) {
                        float sr = __shfl(scale, (r & 3) + 8 * (r >> 2) + 4 * hi);
                        oacc[0][r] *= sr; oacc[1][r] *= sr;
                        oacc[2][r] *= sr; oacc[3][r] *= sr;
                    }
                }
                float ps = 0.f;
                #pragma unroll
                for (int r = 0; r < 16; ++r) { p[r] = __expf(p[r] - m_s); ps += p[r]; }
                l_s += ps;

                // P -> PV A-frags in-register
                half8 pa[2];
                #pragma unroll
                for (int c = 0; c < 2; ++c) {
                    uint32_t u0 = pk16(p[8*c+0], p[8*c+1]);
                    uint32_t u1 = pk16(p[8*c+2], p[8*c+3]);
                    uint32_t u2 = pk16(p[8*c+4], p[8*c+5]);
                    uint32_t u3 = pk16(p[8*c+6], p[8*c+7]);
                    uint32_t x0 = (uint32_t)__shfl_xor((int)u0, 32);
                    uint32_t x1 = (uint32_t)__shfl_xor((int)u1, 32);
                    uint32_t x2 = (uint32_t)__shfl_xor((int)u2, 32);
                    uint32_t x3 = (uint32_t)__shfl_xor((int)u3, 32);
                    uint4v fw;
                    if (hi == 0) { fw[0] = u0; fw[1] = u1; fw[2] = x0; fw[3] = x1; }
                    else         { fw[0] = x2; fw[1] = x3; fw[2] = u2; fw[3] = u3; }
                    pa[c] = __builtin_bit_cast(half8, fw);
                }

                // P @ V
                #pragma unroll
                for (int db = 0; db < 4; ++db)
                    #pragma unroll
                    for (int c = 0; c < 2; ++c) {
                        half8 vb8 = *reinterpret_cast<const half8*>(
                            vsb + (2 * c + hi) * 2048 + (db * 32 + qn) * 16);
                        oacc[db] = __builtin_amdgcn_mfma_f32_32x32x16_f16(pa[c], vb8, oacc[db], 0, 0, 0);
                    }
            }
            asm volatile("s_waitcnt lgkmcnt(0)" ::: "memory");  // WAR guard
            __builtin_amdgcn_s_barrier();
        }
        // drain dummy DMAs before next rep's prologue rewrites the same LDS
        asm volatile("s_waitcnt vmcnt(0)" ::: "memory");
        __builtin_amdgcn_s_barrier();
    }

    l_s += __shfl_xor(l_s, 32);

    // -------- merge halves (arena aliases dead staging LDS) --------
    if (hseg == 1) {
        float* mo = mrg_o + (size_t)(qsel * 64 + lane) * 68;
        #pragma unroll
        for (int db = 0; db < 4; ++db)
            #pragma unroll
            for (int r = 0; r < 16; ++r) mo[db * 16 + r] = oacc[db][r];
        mrg_ml[(qsel * 64 + lane) * 2 + 0] = m_s;
        mrg_ml[(qsel * 64 + lane) * 2 + 1] = l_s;
    }
    __syncthreads();
    if (hseg == 0) {
        float m1 = mrg_ml[(qsel * 64 + lane) * 2 + 0];
        float l1 = mrg_ml[(qsel * 64 + lane) * 2 + 1];
        float mm = fmaxf(m_s, m1);
        float e0 = __expf(m_s - mm);
        float e1 = __expf(m1 - mm);
        float inv = 1.f / (l_s * e0 + l1 * e1);
        float sc0 = e0 * inv, sc1 = e1 * inv;
        const float* mo = mrg_o + (size_t)(qsel * 64 + lane) * 68;
        #pragma unroll
        for (int r = 0; r < 16; ++r) {
            int qr = (r & 3) + 8 * (r >> 2) + 4 * hi;
            float s0r = __shfl(sc0, qr);
            float s1r = __shfl(sc1, qr);
            float* orow = Oh + ((size_t)(q0 + qr) << 7) + qn;
            #pragma unroll
            for (int db = 0; db < 4; ++db)
                orow[db * 32] = oacc[db][r] * s0r + mo[db * 16 + r] * s1r;
        }
    }
#undef STAGE1
}

extern "C" void kernel_launch(void* const* d_in, const int* in_sizes, int n_in,
                              void* d_out, int out_size, void* d_ws, size_t ws_size,
                              hipStream_t stream) {
    (void)in_sizes; (void)n_in; (void)out_size; (void)ws_size;
    const float* q = (const float*)d_in[0];
    const float* k = (const float*)d_in[1];
    const float* v = (const float*)d_in[2];
    // d_in[3] = mask: structural (causal sliding window, W=512) — never read.
    float* o = (float*)d_out;

    _Float16* kf = (_Float16*)d_ws;
    _Float16* vt = kf + HSD;

    hipLaunchKernelGGL(prep, dim3(S_LEN / 32, D_DIM / 32, H_NUM), dim3(256), 0, stream,
                       k, v, kf, vt);
    hipLaunchKernelGGL(swa_fwd, dim3(NWG), dim3(512), 0, stream, q, kf, vt, o);
}

// Round 12
// 45.869 us; speedup vs baseline: 1.3613x; 1.3613x over previous
//
#include <hip/hip_runtime.h>
#include <hip/hip_bf16.h>
#include <stdint.h>

#define H_NUM 16
#define S_LEN 2048
#define D_DIM 128
#define WIN   512
#define HSD   (H_NUM * S_LEN * D_DIM)   // 4194304 elements
#define VSTRIDE (S_LEN + 8)             // padded Vt row stride (r4 fix)
#define NWG   512                       // 16 heads x 32 groups(64 rows)

typedef __attribute__((ext_vector_type(8)))  _Float16 half8;
typedef __attribute__((ext_vector_type(4)))  _Float16 half4;
typedef __attribute__((ext_vector_type(2)))  __fp16   fp16x2;
typedef __attribute__((ext_vector_type(4)))  float f32x4;
typedef __attribute__((ext_vector_type(16))) float f32x16;
typedef __attribute__((ext_vector_type(4)))  unsigned int uint4v;

static __device__ __forceinline__ void gload16(const void* g, void* l) {
    __builtin_amdgcn_global_load_lds(
        (const __attribute__((address_space(1))) uint32_t*)g,
        (__attribute__((address_space(3))) uint32_t*)l, 16, 0, 0);
}
static __device__ __forceinline__ uint32_t pk16(float a, float b) {
    fp16x2 t = __builtin_amdgcn_cvt_pkrtz(a, b);   // v_cvt_pkrtz_f16_f32
    return __builtin_bit_cast(uint32_t, t);
}

// ---- fused pre-pass: K fp32->fp16 (streaming) + V transpose (32x32 fp32 tile,
// conflict-free reads) ----  [r11-proven]
__global__ __launch_bounds__(256) void prep(
    const float* __restrict__ K, const float* __restrict__ V,
    _Float16* __restrict__ kf, _Float16* __restrict__ vt)
{
    __shared__ float t[32][33];
    int h = blockIdx.z, s0 = blockIdx.x * 32, d0 = blockIdx.y * 32;
    int tid = threadIdx.x;

    size_t blk = ((size_t)blockIdx.z * gridDim.y + blockIdx.y) * gridDim.x + blockIdx.x;
    size_t ki = (blk * 256 + tid) * 4;
    float4 kx = *reinterpret_cast<const float4*>(K + ki);
    half4 kh4 = {(_Float16)kx.x, (_Float16)kx.y, (_Float16)kx.z, (_Float16)kx.w};
    *reinterpret_cast<half4*>(kf + ki) = kh4;

    int r = tid >> 3;
    int c = (tid & 7) * 4;
    float4 x = *reinterpret_cast<const float4*>(
        V + ((size_t)(h * S_LEN + s0 + r) << 7) + d0 + c);
    t[r][c + 0] = x.x; t[r][c + 1] = x.y; t[r][c + 2] = x.z; t[r][c + 3] = x.w;
    __syncthreads();
    half4 y;
    #pragma unroll
    for (int e = 0; e < 4; ++e) y[e] = (_Float16)t[c + e][r];
    *reinterpret_cast<half4*>(vt + (size_t)(h * D_DIM + d0 + r) * VSTRIDE + s0 + c) = y;
}

// ---- main: 4 waves/WG = 2 q-tiles(32) x 2 window-halves; 32x32 MFMA ----
// 512 WGs x 256 thr -> 2 WGs/CU: two INDEPENDENT 4-wave barrier groups per CU
// (r12 change: break the single-WG 8-wave lockstep; wave-level code unchanged).
// mfma_f32_32x32x16_f16: A row=lane&31,k=(lane>>5)*8+e; B col=lane&31,same k;
// C/D col=lane&31, row=(reg&3)+8*(reg>>2)+4*(lane>>5).
__global__ __launch_bounds__(256, 2) void swa_fwd(
    const float* __restrict__ Q, const _Float16* __restrict__ kf,
    const _Float16* __restrict__ vt, float* __restrict__ O)
{
    __shared__ __align__(16) char arena[66560];
    char* ksL = arena;                          // [2][8192] K low
    char* vsL = arena + 16384;                  // [2][8192] V low
    char* ksH = arena + 32768;                  // [2][8192] K high
    char* vsH = arena + 49152;                  // [2][8192] V high
    float* mrg_o  = (float*)arena;              // [2][64][68] (post-loop alias)
    float* mrg_ml = (float*)(arena + 65536);    // [2][64][2]

    int bid = blockIdx.x;
    int wid = ((bid & 7) << 6) | (bid >> 3);    // XCD-bijective (512%8==0)
    int h    = wid >> 5;
    int q0wg = (wid & 31) << 6;                 // 64 q-rows per WG

    int tid  = threadIdx.x;
    int wv   = tid >> 6;          // 0..3
    int lane = tid & 63;
    int qn = lane & 31;
    int hi = lane >> 5;
    int qsel = wv & 1;
    int hseg = wv >> 1;
    int q0 = q0wg + qsel * 32;

    const float*    Qh = Q  + ((size_t)h << 18);
    const char*     Kb = (const char*)(kf + ((size_t)h << 18));
    const char*     Vb = (const char*)(vt + (size_t)h * D_DIM * VSTRIDE);
    float*          Oh = O  + ((size_t)h << 18);

    half8 qa[8];
    const float* qrow = Qh + ((size_t)(q0 + qn) << 7) + hi * 8;
    #pragma unroll
    for (int c = 0; c < 8; ++c) {
        float4 a0 = *reinterpret_cast<const float4*>(qrow + c * 16);
        float4 a1 = *reinterpret_cast<const float4*>(qrow + c * 16 + 4);
        qa[c] = (half8){(_Float16)a0.x, (_Float16)a0.y, (_Float16)a0.z, (_Float16)a0.w,
                        (_Float16)a1.x, (_Float16)a1.y, (_Float16)a1.z, (_Float16)a1.w};
    }

    f32x16 oacc[4];
    #pragma unroll
    for (int db = 0; db < 4; ++db)
        #pragma unroll
        for (int i = 0; i < 16; ++i) oacc[db][i] = 0.f;
    float m_s = -1e30f, l_s = 0.f;

    int kstart = q0wg - (WIN - 1);
    if (kstart < 0) kstart = 0;
    kstart &= ~31;
    int nt  = ((q0wg + 64) - kstart) >> 5;
    int nt0 = (nt + 1) >> 1;
    int ntH = nt - nt0;                  // >= 1 (min nt = 2)
    int iq   = q0 + qn;
    int w_ks = q0 - (WIN - 1);
    int w_ke = q0 + 32;

    // 4 waves fill an 8KB K-tile + 8KB V-tile: 2 K-slots + 2 V-slots per wave
    // (4 gload16/wave/call; 2 calls/iter -> vmcnt(8) waits the previous iter's 8).
#define STAGE1(KS, VS, BUF, KB_) do {                                            \
        _Pragma("unroll")                                                        \
        for (int i_ = 0; i_ < 2; ++i_) {                                         \
            int sb_ = (wv * 2 + i_) * 1024 + lane * 16;                          \
            int kr_ = sb_ >> 8;                                                  \
            int kc_ = (sb_ & 255) ^ ((kr_ & 7) << 4);                            \
            gload16(Kb + (((size_t)((KB_) + kr_)) << 8) + kc_,                   \
                    (KS) + (BUF) * 8192 + (wv * 2 + i_) * 1024);                 \
            int vs_ = sb_ >> 11;                                                 \
            int vd_ = (sb_ >> 4) & 127;                                          \
            gload16(Vb + (size_t)vd_ * (VSTRIDE * 2) + (size_t)((KB_) + vs_ * 8) * 2,\
                    (VS) + (BUF) * 8192 + (wv * 2 + i_) * 1024);                 \
        }                                                                        \
    } while (0)

    STAGE1(ksL, vsL, 0, kstart);
    STAGE1(ksH, vsH, 0, kstart + nt0 * 32);

    int my_cnt = hseg ? ntH : nt0;
    for (int it = 0; it < nt0; ++it) {
        int cur = it & 1;
        int nxt = cur ^ 1;
        int pfL = (it + 1 < nt0) ? it + 1 : nt0 - 1;   // clamped dummy keeps
        int pfH = (it + 1 < ntH) ? it + 1 : ntH - 1;   // vmcnt uniform (8/iter)
        STAGE1(ksL, vsL, nxt, kstart + pfL * 32);
        STAGE1(ksH, vsH, nxt, kstart + (nt0 + pfH) * 32);

        asm volatile("s_waitcnt vmcnt(8)" ::: "memory");  // prev 8 done; 8 in flight
        __builtin_amdgcn_s_barrier();
        __builtin_amdgcn_sched_barrier(0);

        int mt = (hseg ? nt0 : 0) + it;
        int kb = kstart + mt * 32;
        bool act = (it < my_cnt) && (kb < w_ke) && (kb + 32 > w_ks);
        if (act) {
            const char* ksb = (hseg ? ksH : ksL) + cur * 8192;
            const char* vsb = (hseg ? vsH : vsL) + cur * 8192;

            // QK^T swapped: D[key][q]
            f32x16 sacc;
            #pragma unroll
            for (int i = 0; i < 16; ++i) sacc[i] = 0.f;
            int sw = (qn & 7) << 4;
            __builtin_amdgcn_s_setprio(1);
            #pragma unroll
            for (int c = 0; c < 8; ++c) {
                half8 kh = *reinterpret_cast<const half8*>(
                    ksb + qn * 256 + ((c * 32 + hi * 16) ^ sw));
                sacc = __builtin_amdgcn_mfma_f32_32x32x16_f16(kh, qa[c], sacc, 0, 0, 0);
            }
            __builtin_amdgcn_s_setprio(0);

            // mask (interior skip) + 16-wide softmax
            float p[16];
            bool fullt = (kb >= q0 - 480) && (kb <= q0 - 31);
            if (fullt) {
                #pragma unroll
                for (int r = 0; r < 16; ++r) p[r] = sacc[r];
            } else {
                #pragma unroll
                for (int r = 0; r < 16; ++r) {
                    int j = kb + (r & 3) + 8 * (r >> 2) + 4 * hi;
                    p[r] = ((j <= iq) && (j + WIN > iq)) ? sacc[r] : -1e30f;
                }
            }
            float tm = p[0];
            #pragma unroll
            for (int r = 1; r < 16; ++r) tm = fmaxf(tm, p[r]);
            tm = fmaxf(tm, __shfl_xor(tm, 32));

            if (!__all(tm - m_s <= 8.f)) {       // T13 defer-max
                float mn = fmaxf(m_s, tm);
                float scale = __expf(m_s - mn);  // 0 wipes fresh-lane junk
                m_s = mn;
                l_s *= scale;
                #pragma unroll
                for (int r = 0; r < 16; ++r) {
                    float sr = __shfl(scale, (r & 3) + 8 * (r >> 2) + 4 * hi);
                    oacc[0][r] *= sr; oacc[1][r] *= sr;
                    oacc[2][r] *= sr; oacc[3][r] *= sr;
                }
            }
            float ps = 0.f;
            #pragma unroll
            for (int r = 0; r < 16; ++r) { p[r] = __expf(p[r] - m_s); ps += p[r]; }
            l_s += ps;

            // P -> PV A-frags in-register (pk + partner shfl)
            half8 pa[2];
            #pragma unroll
            for (int c = 0; c < 2; ++c) {
                uint32_t u0 = pk16(p[8*c+0], p[8*c+1]);
                uint32_t u1 = pk16(p[8*c+2], p[8*c+3]);
                uint32_t u2 = pk16(p[8*c+4], p[8*c+5]);
                uint32_t u3 = pk16(p[8*c+6], p[8*c+7]);
                uint32_t x0 = (uint32_t)__shfl_xor((int)u0, 32);
                uint32_t x1 = (uint32_t)__shfl_xor((int)u1, 32);
                uint32_t x2 = (uint32_t)__shfl_xor((int)u2, 32);
                uint32_t x3 = (uint32_t)__shfl_xor((int)u3, 32);
                uint4v fw;
                if (hi == 0) { fw[0] = u0; fw[1] = u1; fw[2] = x0; fw[3] = x1; }
                else         { fw[0] = x2; fw[1] = x3; fw[2] = u2; fw[3] = u3; }
                pa[c] = __builtin_bit_cast(half8, fw);
            }

            // P @ V
            __builtin_amdgcn_s_setprio(1);
            #pragma unroll
            for (int db = 0; db < 4; ++db)
                #pragma unroll
                for (int c = 0; c < 2; ++c) {
                    half8 vb8 = *reinterpret_cast<const half8*>(
                        vsb + (2 * c + hi) * 2048 + (db * 32 + qn) * 16);
                    oacc[db] = __builtin_amdgcn_mfma_f32_32x32x16_f16(pa[c], vb8, oacc[db], 0, 0, 0);
                }
            __builtin_amdgcn_s_setprio(0);
        }
        asm volatile("s_waitcnt lgkmcnt(0)" ::: "memory");  // WAR guard
        __builtin_amdgcn_s_barrier();
    }

    l_s += __shfl_xor(l_s, 32);
    asm volatile("s_waitcnt vmcnt(0)" ::: "memory");   // drain dummy DMAs
    __builtin_amdgcn_s_barrier();                      // before arena alias

    // -------- merge halves (arena aliases dead staging LDS) --------
    if (hseg == 1) {
        float* mo = mrg_o + (size_t)(qsel * 64 + lane) * 68;
        #pragma unroll
        for (int db = 0; db < 4; ++db)
            #pragma unroll
            for (int r = 0; r < 16; ++r) mo[db * 16 + r] = oacc[db][r];
        mrg_ml[(qsel * 64 + lane) * 2 + 0] = m_s;
        mrg_ml[(qsel * 64 + lane) * 2 + 1] = l_s;
    }
    __syncthreads();
    if (hseg == 0) {
        float m1 = mrg_ml[(qsel * 64 + lane) * 2 + 0];
        float l1 = mrg_ml[(qsel * 64 + lane) * 2 + 1];
        float mm = fmaxf(m_s, m1);
        float e0 = __expf(m_s - mm);
        float e1 = __expf(m1 - mm);
        float inv = 1.f / (l_s * e0 + l1 * e1);
        float sc0 = e0 * inv, sc1 = e1 * inv;
        const float* mo = mrg_o + (size_t)(qsel * 64 + lane) * 68;
        #pragma unroll
        for (int r = 0; r < 16; ++r) {
            int qr = (r & 3) + 8 * (r >> 2) + 4 * hi;
            float s0r = __shfl(sc0, qr);
            float s1r = __shfl(sc1, qr);
            float* orow = Oh + ((size_t)(q0 + qr) << 7) + qn;
            #pragma unroll
            for (int db = 0; db < 4; ++db)
                orow[db * 32] = oacc[db][r] * s0r + mo[db * 16 + r] * s1r;
        }
    }
#undef STAGE1
}

extern "C" void kernel_launch(void* const* d_in, const int* in_sizes, int n_in,
                              void* d_out, int out_size, void* d_ws, size_t ws_size,
                              hipStream_t stream) {
    (void)in_sizes; (void)n_in; (void)out_size; (void)ws_size;
    const float* q = (const float*)d_in[0];
    const float* k = (const float*)d_in[1];
    const float* v = (const float*)d_in[2];
    // d_in[3] = mask: structural (causal sliding window, W=512) — never read.
    float* o = (float*)d_out;

    _Float16* kf = (_Float16*)d_ws;
    _Float16* vt = kf + HSD;

    hipLaunchKernelGGL(prep, dim3(S_LEN / 32, D_DIM / 32, H_NUM), dim3(256), 0, stream,
                       k, v, kf, vt);
    hipLaunchKernelGGL(swa_fwd, dim3(NWG), dim3(256), 0, stream, q, kf, vt, o);
}

// Round 13
// 44.583 us; speedup vs baseline: 1.4005x; 1.0288x over previous
//
#include <hip/hip_runtime.h>
#include <hip/hip_bf16.h>
#include <stdint.h>

#define H_NUM 16
#define S_LEN 2048
#define D_DIM 128
#define WIN   512
#define HSD   (H_NUM * S_LEN * D_DIM)   // 4194304 elements
#define VSTRIDE (S_LEN + 8)             // padded Vt row stride (r4 fix)
#define NWG   256                       // 16 heads x 16 q-groups(128 rows)
#define LOG2E 1.4426950408889634f

typedef __attribute__((ext_vector_type(8)))  _Float16 half8;
typedef __attribute__((ext_vector_type(4)))  _Float16 half4;
typedef __attribute__((ext_vector_type(2)))  __fp16   fp16x2;
typedef __attribute__((ext_vector_type(4)))  float f32x4;
typedef __attribute__((ext_vector_type(16))) float f32x16;
typedef __attribute__((ext_vector_type(4)))  unsigned int uint4v;

static __device__ __forceinline__ void gload16(const void* g, void* l) {
    __builtin_amdgcn_global_load_lds(
        (const __attribute__((address_space(1))) uint32_t*)g,
        (__attribute__((address_space(3))) uint32_t*)l, 16, 0, 0);
}
static __device__ __forceinline__ uint32_t pk16(float a, float b) {
    fp16x2 t = __builtin_amdgcn_cvt_pkrtz(a, b);   // v_cvt_pkrtz_f16_f32
    return __builtin_bit_cast(uint32_t, t);
}
static __device__ __forceinline__ float fexp2(float x) {
#if __has_builtin(__builtin_amdgcn_exp2f)
    return __builtin_amdgcn_exp2f(x);              // bare v_exp_f32
#else
    return exp2f(x);
#endif
}

// ---- fused pre-pass: K fp32->fp16 (streaming) + V transpose (32x32 fp32 tile,
// conflict-free reads) ----  [r11-proven, ~8us]
__global__ __launch_bounds__(256) void prep(
    const float* __restrict__ K, const float* __restrict__ V,
    _Float16* __restrict__ kf, _Float16* __restrict__ vt)
{
    __shared__ float t[32][33];
    int h = blockIdx.z, s0 = blockIdx.x * 32, d0 = blockIdx.y * 32;
    int tid = threadIdx.x;

    size_t blk = ((size_t)blockIdx.z * gridDim.y + blockIdx.y) * gridDim.x + blockIdx.x;
    size_t ki = (blk * 256 + tid) * 4;
    float4 kx = *reinterpret_cast<const float4*>(K + ki);
    half4 kh4 = {(_Float16)kx.x, (_Float16)kx.y, (_Float16)kx.z, (_Float16)kx.w};
    *reinterpret_cast<half4*>(kf + ki) = kh4;

    int r = tid >> 3;
    int c = (tid & 7) * 4;
    float4 x = *reinterpret_cast<const float4*>(
        V + ((size_t)(h * S_LEN + s0 + r) << 7) + d0 + c);
    t[r][c + 0] = x.x; t[r][c + 1] = x.y; t[r][c + 2] = x.z; t[r][c + 3] = x.w;
    __syncthreads();
    half4 y;
    #pragma unroll
    for (int e = 0; e < 4; ++e) y[e] = (_Float16)t[c + e][r];
    *reinterpret_cast<half4*>(vt + (size_t)(h * D_DIM + d0 + r) * VSTRIDE + s0 + c) = y;
}

// ---- main: 8 waves/WG = 4 q-tiles(32) x 2 window-halves; 32x32 MFMA ----
// r13: r11 geometry restored; single __syncthreads per iter (STAGE after it);
// exp2-domain softmax (Q pre-scaled by log2e); max3-tree reduce; permlane32_swap.
// mfma_f32_32x32x16_f16: A row=lane&31,k=(lane>>5)*8+e; B col=lane&31,same k;
// C/D col=lane&31, row=(reg&3)+8*(reg>>2)+4*(lane>>5).
__global__ __launch_bounds__(512, 2) void swa_fwd(
    const float* __restrict__ Q, const _Float16* __restrict__ kf,
    const _Float16* __restrict__ vt, float* __restrict__ O)
{
    __shared__ __align__(16) char arena[71680];
    char* ksL = arena;                          // [2][8192] K low
    char* vsL = arena + 16384;                  // [2][8192] V low
    char* ksH = arena + 32768;                  // [2][8192] K high
    char* vsH = arena + 49152;                  // [2][8192] V high
    float* mrg_o  = (float*)arena;              // [4][64][68] (post-loop alias)
    float* mrg_ml = (float*)(arena + 69632);    // [4][64][2]

    int bid = blockIdx.x;
    int wid = ((bid & 7) << 5) | (bid >> 3);    // XCD-bijective (256%8==0)
    int h    = wid >> 4;
    int q0wg = (wid & 15) << 7;

    int tid  = threadIdx.x;
    int wv   = tid >> 6;
    int lane = tid & 63;
    int qn = lane & 31;
    int hi = lane >> 5;
    int qsel = wv & 3;
    int hseg = wv >> 2;
    int q0 = q0wg + qsel * 32;

    const float*    Qh = Q  + ((size_t)h << 18);
    const char*     Kb = (const char*)(kf + ((size_t)h << 18));
    const char*     Vb = (const char*)(vt + (size_t)h * D_DIM * VSTRIDE);
    float*          Oh = O  + ((size_t)h << 18);

    // Q fragments, pre-scaled by log2e: QK^T lands in exp2 domain.
    half8 qa[8];
    const float* qrow = Qh + ((size_t)(q0 + qn) << 7) + hi * 8;
    #pragma unroll
    for (int c = 0; c < 8; ++c) {
        float4 a0 = *reinterpret_cast<const float4*>(qrow + c * 16);
        float4 a1 = *reinterpret_cast<const float4*>(qrow + c * 16 + 4);
        qa[c] = (half8){(_Float16)(a0.x * LOG2E), (_Float16)(a0.y * LOG2E),
                        (_Float16)(a0.z * LOG2E), (_Float16)(a0.w * LOG2E),
                        (_Float16)(a1.x * LOG2E), (_Float16)(a1.y * LOG2E),
                        (_Float16)(a1.z * LOG2E), (_Float16)(a1.w * LOG2E)};
    }

    f32x16 oacc[4];
    #pragma unroll
    for (int db = 0; db < 4; ++db)
        #pragma unroll
        for (int i = 0; i < 16; ++i) oacc[db][i] = 0.f;
    float m_s = -1e30f, l_s = 0.f;

    int kstart = q0wg - (WIN - 1);
    if (kstart < 0) kstart = 0;
    kstart &= ~31;
    int nt  = ((q0wg + 128) - kstart) >> 5;
    int nt0 = (nt + 1) >> 1;
    int ntH = nt - nt0;                  // >= 1
    int iq   = q0 + qn;
    int w_ks = q0 - (WIN - 1);
    int w_ke = q0 + 32;

#define STAGE1(KS, VS, BUF, KB_) do {                                            \
        int sb_ = wv * 1024 + lane * 16;                                         \
        int kr_ = sb_ >> 8;                                                      \
        int kc_ = (sb_ & 255) ^ ((kr_ & 7) << 4);                                \
        gload16(Kb + (((size_t)((KB_) + kr_)) << 8) + kc_,                       \
                (KS) + (BUF) * 8192 + wv * 1024);                                \
        int vs_ = sb_ >> 11;                                                     \
        int vd_ = (sb_ >> 4) & 127;                                              \
        gload16(Vb + (size_t)vd_ * (VSTRIDE * 2) + (size_t)((KB_) + vs_ * 8) * 2,\
                (VS) + (BUF) * 8192 + wv * 1024);                                \
    } while (0)

    STAGE1(ksL, vsL, 0, kstart);
    STAGE1(ksH, vsH, 0, kstart + nt0 * 32);

    int my_cnt = hseg ? ntH : nt0;
    for (int it = 0; it < nt0; ++it) {
        int cur = it & 1;
        // Single rendezvous: drains prev-iter DMAs (RAW) + prev-iter LDS reads (WAR).
        // The drained loads were issued a full iteration ago -> near-free.
        __syncthreads();
        if (it + 1 < nt0) STAGE1(ksL, vsL, cur ^ 1, kstart + (it + 1) * 32);
        if (it + 1 < ntH) STAGE1(ksH, vsH, cur ^ 1, kstart + (nt0 + it + 1) * 32);

        int mt = (hseg ? nt0 : 0) + it;
        int kb = kstart + mt * 32;
        bool act = (it < my_cnt) && (kb < w_ke) && (kb + 32 > w_ks);
        if (act) {
            const char* ksb = (hseg ? ksH : ksL) + cur * 8192;
            const char* vsb = (hseg ? vsH : vsL) + cur * 8192;

            // QK^T swapped: D[key][q] in exp2 domain
            f32x16 sacc;
            #pragma unroll
            for (int i = 0; i < 16; ++i) sacc[i] = 0.f;
            int sw = (qn & 7) << 4;
            #pragma unroll
            for (int c = 0; c < 8; ++c) {
                half8 kh = *reinterpret_cast<const half8*>(
                    ksb + qn * 256 + ((c * 32 + hi * 16) ^ sw));
                sacc = __builtin_amdgcn_mfma_f32_32x32x16_f16(kh, qa[c], sacc, 0, 0, 0);
            }

            // mask (interior skip)
            float p[16];
            bool fullt = (kb >= q0 - 480) && (kb <= q0 - 31);
            if (fullt) {
                #pragma unroll
                for (int r = 0; r < 16; ++r) p[r] = sacc[r];
            } else {
                #pragma unroll
                for (int r = 0; r < 16; ++r) {
                    int j = kb + (r & 3) + 8 * (r >> 2) + 4 * hi;
                    p[r] = ((j <= iq) && (j + WIN > iq)) ? sacc[r] : -1e30f;
                }
            }
            // row max: max3 tree (depth 3)
            float t0 = fmaxf(fmaxf(p[0], p[1]), p[2]);
            float t1 = fmaxf(fmaxf(p[3], p[4]), p[5]);
            float t2 = fmaxf(fmaxf(p[6], p[7]), p[8]);
            float t3 = fmaxf(fmaxf(p[9], p[10]), p[11]);
            float t4 = fmaxf(fmaxf(p[12], p[13]), p[14]);
            float tm = fmaxf(fmaxf(fmaxf(t0, t1), fmaxf(t2, t3)), fmaxf(t4, p[15]));
            tm = fmaxf(tm, __shfl_xor(tm, 32));   // pair covers all 32 keys

            // T13 defer-max, threshold 8*log2e (forced rescale wipes fresh-lane junk)
            if (!__all(tm - m_s <= 11.5424f)) {
                float mn = fmaxf(m_s, tm);
                float scale = fexp2(m_s - mn);    // 0 for fresh lanes
                m_s = mn;
                l_s *= scale;
                #pragma unroll
                for (int r = 0; r < 16; ++r) {
                    float sr = __shfl(scale, (r & 3) + 8 * (r >> 2) + 4 * hi);
                    oacc[0][r] *= sr; oacc[1][r] *= sr;
                    oacc[2][r] *= sr; oacc[3][r] *= sr;
                }
            }
            #pragma unroll
            for (int r = 0; r < 16; ++r) p[r] = fexp2(p[r] - m_s);
            // l-sum: pairwise tree (depth 4)
            {
                float s0 = (p[0] + p[1]) + (p[2] + p[3]);
                float s1 = (p[4] + p[5]) + (p[6] + p[7]);
                float s2 = (p[8] + p[9]) + (p[10] + p[11]);
                float s3 = (p[12] + p[13]) + (p[14] + p[15]);
                l_s += (s0 + s1) + (s2 + s3);
            }

            // P -> PV A-frags in-register.
            // swap(u0,u2) = {fw0, fw2}; swap(u1,u3) = {fw1, fw3}  (derivation r13)
            half8 pa[2];
            #pragma unroll
            for (int c = 0; c < 2; ++c) {
                uint32_t u0 = pk16(p[8*c+0], p[8*c+1]);
                uint32_t u1 = pk16(p[8*c+2], p[8*c+3]);
                uint32_t u2 = pk16(p[8*c+4], p[8*c+5]);
                uint32_t u3 = pk16(p[8*c+6], p[8*c+7]);
                uint4v fw;
#if __has_builtin(__builtin_amdgcn_permlane32_swap)
                auto w02 = __builtin_amdgcn_permlane32_swap(u0, u2, false, false);
                auto w13 = __builtin_amdgcn_permlane32_swap(u1, u3, false, false);
                fw[0] = (uint32_t)w02[0]; fw[2] = (uint32_t)w02[1];
                fw[1] = (uint32_t)w13[0]; fw[3] = (uint32_t)w13[1];
#else
                uint32_t x0 = (uint32_t)__shfl_xor((int)u0, 32);
                uint32_t x1 = (uint32_t)__shfl_xor((int)u1, 32);
                uint32_t x2 = (uint32_t)__shfl_xor((int)u2, 32);
                uint32_t x3 = (uint32_t)__shfl_xor((int)u3, 32);
                if (hi == 0) { fw[0] = u0; fw[1] = u1; fw[2] = x0; fw[3] = x1; }
                else         { fw[0] = x2; fw[1] = x3; fw[2] = u2; fw[3] = u3; }
#endif
                pa[c] = __builtin_bit_cast(half8, fw);
            }

            // P @ V
            #pragma unroll
            for (int db = 0; db < 4; ++db)
                #pragma unroll
                for (int c = 0; c < 2; ++c) {
                    half8 vb8 = *reinterpret_cast<const half8*>(
                        vsb + (2 * c + hi) * 2048 + (db * 32 + qn) * 16);
                    oacc[db] = __builtin_amdgcn_mfma_f32_32x32x16_f16(pa[c], vb8, oacc[db], 0, 0, 0);
                }
        }
    }

    l_s += __shfl_xor(l_s, 32);
    __syncthreads();   // final-iter LDS reads done before arena alias (no DMAs in flight)

    // -------- merge halves (arena aliases dead staging LDS) --------
    if (hseg == 1) {
        float* mo = mrg_o + (size_t)(qsel * 64 + lane) * 68;
        #pragma unroll
        for (int db = 0; db < 4; ++db)
            #pragma unroll
            for (int r = 0; r < 16; ++r) mo[db * 16 + r] = oacc[db][r];
        mrg_ml[(qsel * 64 + lane) * 2 + 0] = m_s;
        mrg_ml[(qsel * 64 + lane) * 2 + 1] = l_s;
    }
    __syncthreads();
    if (hseg == 0) {
        float m1 = mrg_ml[(qsel * 64 + lane) * 2 + 0];
        float l1 = mrg_ml[(qsel * 64 + lane) * 2 + 1];
        float mm = fmaxf(m_s, m1);
        float e0 = fexp2(m_s - mm);
        float e1 = fexp2(m1 - mm);
        float inv = 1.f / (l_s * e0 + l1 * e1);
        float sc0 = e0 * inv, sc1 = e1 * inv;
        const float* mo = mrg_o + (size_t)(qsel * 64 + lane) * 68;
        #pragma unroll
        for (int r = 0; r < 16; ++r) {
            int qr = (r & 3) + 8 * (r >> 2) + 4 * hi;
            float s0r = __shfl(sc0, qr);
            float s1r = __shfl(sc1, qr);
            float* orow = Oh + ((size_t)(q0 + qr) << 7) + qn;
            #pragma unroll
            for (int db = 0; db < 4; ++db)
                orow[db * 32] = oacc[db][r] * s0r + mo[db * 16 + r] * s1r;
        }
    }
#undef STAGE1
}

extern "C" void kernel_launch(void* const* d_in, const int* in_sizes, int n_in,
                              void* d_out, int out_size, void* d_ws, size_t ws_size,
                              hipStream_t stream) {
    (void)in_sizes; (void)n_in; (void)out_size; (void)ws_size;
    const float* q = (const float*)d_in[0];
    const float* k = (const float*)d_in[1];
    const float* v = (const float*)d_in[2];
    // d_in[3] = mask: structural (causal sliding window, W=512) — never read.
    float* o = (float*)d_out;

    _Float16* kf = (_Float16*)d_ws;
    _Float16* vt = kf + HSD;

    hipLaunchKernelGGL(prep, dim3(S_LEN / 32, D_DIM / 32, H_NUM), dim3(256), 0, stream,
                       k, v, kf, vt);
    hipLaunchKernelGGL(swa_fwd, dim3(NWG), dim3(512), 0, stream, q, kf, vt, o);
}

// Round 14
// 32.620 us; speedup vs baseline: 1.9142x; 1.3668x over previous
//
#include <hip/hip_runtime.h>
#include <hip/hip_bf16.h>
#include <stdint.h>

#define H_NUM 16
#define S_LEN 2048
#define D_DIM 128
#define WIN   512
#define NWG   256                       // 16 heads x 16 q-groups(128 rows)
#define LOG2E 1.4426950408889634f

typedef __attribute__((ext_vector_type(8)))  _Float16 half8;
typedef __attribute__((ext_vector_type(2)))  __fp16   fp16x2;
typedef __attribute__((ext_vector_type(16))) float f32x16;
typedef __attribute__((ext_vector_type(4)))  unsigned int uint4v;

static __device__ __forceinline__ uint32_t pk16(float a, float b) {
    fp16x2 t = __builtin_amdgcn_cvt_pkrtz(a, b);   // v_cvt_pkrtz_f16_f32
    return __builtin_bit_cast(uint32_t, t);
}
static __device__ __forceinline__ float fexp2(float x) {
#if __has_builtin(__builtin_amdgcn_exp2f)
    return __builtin_amdgcn_exp2f(x);
#else
    return exp2f(x);
#endif
}

// ---- single kernel: flash SWA with in-kernel fp32->fp16 K convert and
// V transpose during LDS staging (prep kernel deleted; d_ws unused).
// 8 waves/WG = 4 q-tiles(32) x 2 window-halves; 32x32 MFMA; single barrier/iter.
// mfma_f32_32x32x16_f16: A row=lane&31,k=(lane>>5)*8+e; B col=lane&31,same k;
// C/D col=lane&31, row=(reg&3)+8*(reg>>2)+4*(lane>>5).
// K LDS [32][256B] XOR-swizzled BOTH sides (G21); V LDS slot-major [4][128][16B].
__global__ __launch_bounds__(512, 2) void swa_fwd(
    const float* __restrict__ Q, const float* __restrict__ K,
    const float* __restrict__ V, float* __restrict__ O)
{
    __shared__ __align__(16) char arena[71680];
    char* ksL = arena;                          // [2][8192] K low
    char* vsL = arena + 16384;                  // [2][8192] V low
    char* ksH = arena + 32768;                  // [2][8192] K high
    char* vsH = arena + 49152;                  // [2][8192] V high
    float* mrg_o  = (float*)arena;              // [4][64][68] (post-loop alias)
    float* mrg_ml = (float*)(arena + 69632);    // [4][64][2]

    int bid = blockIdx.x;
    int wid = ((bid & 7) << 5) | (bid >> 3);    // XCD-bijective (256%8==0)
    int h    = wid >> 4;
    int q0wg = (wid & 15) << 7;

    int tid  = threadIdx.x;
    int wv   = tid >> 6;
    int lane = tid & 63;
    int qn = lane & 31;
    int hi = lane >> 5;
    int qsel = wv & 3;
    int hseg = wv >> 2;
    int q0 = q0wg + qsel * 32;

    const float* Qh = Q + ((size_t)h << 18);
    const float* Kg = K + ((size_t)h << 18);
    const float* Vg = V + ((size_t)h << 18);
    float*       Oh = O + ((size_t)h << 18);

    // staging thread maps (512 threads cover one 8KB fp16 tile per stream)
    int tK_r = tid >> 4;                        // K row 0..31
    int tK_d = (tid & 15) * 8;                  // K d0
    int tK_byte = tK_r * 256 + (((tid & 15) * 16) ^ ((tK_r & 7) << 4));
    int tV_d = (tid >> 4) * 4;                  // V d0 0..124
    int tV_s = (tid & 15) * 2;                  // V s0 0..30 (even)
    int tV_byte = (tV_s >> 3) * 2048 + tV_d * 16 + (tV_s & 7) * 2;

#define K_LOAD(A0, A1, KB_) do {                                               \
        const float* sp_ = Kg + ((size_t)((KB_) + tK_r) << 7) + tK_d;          \
        A0 = *reinterpret_cast<const float4*>(sp_);                            \
        A1 = *reinterpret_cast<const float4*>(sp_ + 4); } while (0)
#define K_WRITE(KS, BUF, A0, A1) do {                                          \
        uint4v u_;                                                             \
        u_[0] = pk16(A0.x, A0.y); u_[1] = pk16(A0.z, A0.w);                    \
        u_[2] = pk16(A1.x, A1.y); u_[3] = pk16(A1.z, A1.w);                    \
        *reinterpret_cast<uint4v*>((KS) + (BUF) * 8192 + tK_byte) = u_; } while (0)
#define V_LOAD(A0, A1, KB_) do {                                               \
        const float* sp_ = Vg + ((size_t)((KB_) + tV_s) << 7) + tV_d;          \
        A0 = *reinterpret_cast<const float4*>(sp_);                            \
        A1 = *reinterpret_cast<const float4*>(sp_ + D_DIM); } while (0)
#define V_WRITE(VS, BUF, A0, A1) do {                                          \
        char* b_ = (VS) + (BUF) * 8192 + tV_byte;                              \
        *reinterpret_cast<uint32_t*>(b_)      = pk16(A0.x, A1.x);              \
        *reinterpret_cast<uint32_t*>(b_ + 16) = pk16(A0.y, A1.y);              \
        *reinterpret_cast<uint32_t*>(b_ + 32) = pk16(A0.z, A1.z);              \
        *reinterpret_cast<uint32_t*>(b_ + 48) = pk16(A0.w, A1.w); } while (0)

    // Q fragments, pre-scaled by log2e (exp2-domain softmax)
    half8 qa[8];
    const float* qrow = Qh + ((size_t)(q0 + qn) << 7) + hi * 8;
    #pragma unroll
    for (int c = 0; c < 8; ++c) {
        float4 a0 = *reinterpret_cast<const float4*>(qrow + c * 16);
        float4 a1 = *reinterpret_cast<const float4*>(qrow + c * 16 + 4);
        qa[c] = (half8){(_Float16)(a0.x * LOG2E), (_Float16)(a0.y * LOG2E),
                        (_Float16)(a0.z * LOG2E), (_Float16)(a0.w * LOG2E),
                        (_Float16)(a1.x * LOG2E), (_Float16)(a1.y * LOG2E),
                        (_Float16)(a1.z * LOG2E), (_Float16)(a1.w * LOG2E)};
    }

    f32x16 oacc[4];
    #pragma unroll
    for (int db = 0; db < 4; ++db)
        #pragma unroll
        for (int i = 0; i < 16; ++i) oacc[db][i] = 0.f;
    float m_s = -1e30f, l_s = 0.f;

    int kstart = q0wg - (WIN - 1);
    if (kstart < 0) kstart = 0;
    kstart &= ~31;
    int nt  = ((q0wg + 128) - kstart) >> 5;
    int nt0 = (nt + 1) >> 1;
    int ntH = nt - nt0;                  // >= 1
    int iq   = q0 + qn;
    int w_ks = q0 - (WIN - 1);
    int w_ke = q0 + 32;

    // prologue: stage tile 0 of both streams (fp32 load -> cvt -> LDS)
    {
        float4 a0, a1;
        K_LOAD(a0, a1, kstart);             K_WRITE(ksL, 0, a0, a1);
        K_LOAD(a0, a1, kstart + nt0 * 32);  K_WRITE(ksH, 0, a0, a1);
        V_LOAD(a0, a1, kstart);             V_WRITE(vsL, 0, a0, a1);
        V_LOAD(a0, a1, kstart + nt0 * 32);  V_WRITE(vsH, 0, a0, a1);
    }

    int my_cnt = hseg ? ntH : nt0;
    for (int it = 0; it < nt0; ++it) {
        int cur = it & 1, nxt = cur ^ 1;
        __syncthreads();   // publishes buf[cur] writes; all prev reads drained

        bool hl = (it + 1 < nt0), hh = (it + 1 < ntH);   // WG-uniform
        // issue next-tile K loads early: latency hides under QK^T
        float4 kl0, kl1, kh0, kh1;
        if (hl) K_LOAD(kl0, kl1, kstart + (it + 1) * 32);
        if (hh) K_LOAD(kh0, kh1, kstart + (nt0 + it + 1) * 32);

        int mt = (hseg ? nt0 : 0) + it;
        int kb = kstart + mt * 32;
        bool act = (it < my_cnt) && (kb < w_ke) && (kb + 32 > w_ks);
        const char* ksb = (hseg ? ksH : ksL) + cur * 8192;
        const char* vsb = (hseg ? vsH : vsL) + cur * 8192;

        f32x16 sacc;
        if (act) {
            #pragma unroll
            for (int i = 0; i < 16; ++i) sacc[i] = 0.f;
            int sw = (qn & 7) << 4;
            #pragma unroll
            for (int c = 0; c < 8; ++c) {
                half8 kh = *reinterpret_cast<const half8*>(
                    ksb + qn * 256 + ((c * 32 + hi * 16) ^ sw));
                sacc = __builtin_amdgcn_mfma_f32_32x32x16_f16(kh, qa[c], sacc, 0, 0, 0);
            }
        }

        // write next K tiles (loads done by now); issue V loads for next tile
        if (hl) K_WRITE(ksL, nxt, kl0, kl1);
        if (hh) K_WRITE(ksH, nxt, kh0, kh1);
        float4 vl0, vl1, vh0, vh1;
        if (hl) V_LOAD(vl0, vl1, kstart + (it + 1) * 32);
        if (hh) V_LOAD(vh0, vh1, kstart + (nt0 + it + 1) * 32);

        if (act) {
            // mask (interior skip)
            float p[16];
            bool fullt = (kb >= q0 - 480) && (kb <= q0 - 31);
            if (fullt) {
                #pragma unroll
                for (int r = 0; r < 16; ++r) p[r] = sacc[r];
            } else {
                #pragma unroll
                for (int r = 0; r < 16; ++r) {
                    int j = kb + (r & 3) + 8 * (r >> 2) + 4 * hi;
                    p[r] = ((j <= iq) && (j + WIN > iq)) ? sacc[r] : -1e30f;
                }
            }
            // row max (max3 tree) + pair exchange
            float t0 = fmaxf(fmaxf(p[0], p[1]), p[2]);
            float t1 = fmaxf(fmaxf(p[3], p[4]), p[5]);
            float t2 = fmaxf(fmaxf(p[6], p[7]), p[8]);
            float t3 = fmaxf(fmaxf(p[9], p[10]), p[11]);
            float t4 = fmaxf(fmaxf(p[12], p[13]), p[14]);
            float tm = fmaxf(fmaxf(fmaxf(t0, t1), fmaxf(t2, t3)), fmaxf(t4, p[15]));
            tm = fmaxf(tm, __shfl_xor(tm, 32));

            // T13 defer-max, threshold 8*log2e (forced rescale wipes fresh-lane junk)
            if (!__all(tm - m_s <= 11.5424f)) {
                float mn = fmaxf(m_s, tm);
                float scale = fexp2(m_s - mn);
                m_s = mn;
                l_s *= scale;
                #pragma unroll
                for (int r = 0; r < 16; ++r) {
                    float sr = __shfl(scale, (r & 3) + 8 * (r >> 2) + 4 * hi);
                    oacc[0][r] *= sr; oacc[1][r] *= sr;
                    oacc[2][r] *= sr; oacc[3][r] *= sr;
                }
            }
            #pragma unroll
            for (int r = 0; r < 16; ++r) p[r] = fexp2(p[r] - m_s);
            {
                float s0 = (p[0] + p[1]) + (p[2] + p[3]);
                float s1 = (p[4] + p[5]) + (p[6] + p[7]);
                float s2 = (p[8] + p[9]) + (p[10] + p[11]);
                float s3 = (p[12] + p[13]) + (p[14] + p[15]);
                l_s += (s0 + s1) + (s2 + s3);
            }

            // P -> PV A-frags in-register (pk + partner exchange)
            half8 pa[2];
            #pragma unroll
            for (int c = 0; c < 2; ++c) {
                uint32_t u0 = pk16(p[8*c+0], p[8*c+1]);
                uint32_t u1 = pk16(p[8*c+2], p[8*c+3]);
                uint32_t u2 = pk16(p[8*c+4], p[8*c+5]);
                uint32_t u3 = pk16(p[8*c+6], p[8*c+7]);
                uint4v fw;
#if __has_builtin(__builtin_amdgcn_permlane32_swap)
                auto w02 = __builtin_amdgcn_permlane32_swap(u0, u2, false, false);
                auto w13 = __builtin_amdgcn_permlane32_swap(u1, u3, false, false);
                fw[0] = (uint32_t)w02[0]; fw[2] = (uint32_t)w02[1];
                fw[1] = (uint32_t)w13[0]; fw[3] = (uint32_t)w13[1];
#else
                uint32_t x0 = (uint32_t)__shfl_xor((int)u0, 32);
                uint32_t x1 = (uint32_t)__shfl_xor((int)u1, 32);
                uint32_t x2 = (uint32_t)__shfl_xor((int)u2, 32);
                uint32_t x3 = (uint32_t)__shfl_xor((int)u3, 32);
                if (hi == 0) { fw[0] = u0; fw[1] = u1; fw[2] = x0; fw[3] = x1; }
                else         { fw[0] = x2; fw[1] = x3; fw[2] = u2; fw[3] = u3; }
#endif
                pa[c] = __builtin_bit_cast(half8, fw);
            }

            // P @ V
            #pragma unroll
            for (int db = 0; db < 4; ++db)
                #pragma unroll
                for (int c = 0; c < 2; ++c) {
                    half8 vb8 = *reinterpret_cast<const half8*>(
                        vsb + (2 * c + hi) * 2048 + (db * 32 + qn) * 16);
                    oacc[db] = __builtin_amdgcn_mfma_f32_32x32x16_f16(pa[c], vb8, oacc[db], 0, 0, 0);
                }
        }

        // write next V tiles (loads covered by softmax+PV span)
        if (hl) V_WRITE(vsL, nxt, vl0, vl1);
        if (hh) V_WRITE(vsH, nxt, vh0, vh1);
    }

    l_s += __shfl_xor(l_s, 32);
    __syncthreads();   // final-iter LDS ops drained before arena alias

    // -------- merge halves (arena aliases dead staging LDS) --------
    if (hseg == 1) {
        float* mo = mrg_o + (size_t)(qsel * 64 + lane) * 68;
        #pragma unroll
        for (int db = 0; db < 4; ++db)
            #pragma unroll
            for (int r = 0; r < 16; ++r) mo[db * 16 + r] = oacc[db][r];
        mrg_ml[(qsel * 64 + lane) * 2 + 0] = m_s;
        mrg_ml[(qsel * 64 + lane) * 2 + 1] = l_s;
    }
    __syncthreads();
    if (hseg == 0) {
        float m1 = mrg_ml[(qsel * 64 + lane) * 2 + 0];
        float l1 = mrg_ml[(qsel * 64 + lane) * 2 + 1];
        float mm = fmaxf(m_s, m1);
        float e0 = fexp2(m_s - mm);
        float e1 = fexp2(m1 - mm);
        float inv = 1.f / (l_s * e0 + l1 * e1);
        float sc0 = e0 * inv, sc1 = e1 * inv;
        const float* mo = mrg_o + (size_t)(qsel * 64 + lane) * 68;
        #pragma unroll
        for (int r = 0; r < 16; ++r) {
            int qr = (r & 3) + 8 * (r >> 2) + 4 * hi;
            float s0r = __shfl(sc0, qr);
            float s1r = __shfl(sc1, qr);
            float* orow = Oh + ((size_t)(q0 + qr) << 7) + qn;
            #pragma unroll
            for (int db = 0; db < 4; ++db)
                orow[db * 32] = oacc[db][r] * s0r + mo[db * 16 + r] * s1r;
        }
    }
#undef K_LOAD
#undef K_WRITE
#undef V_LOAD
#undef V_WRITE
}

extern "C" void kernel_launch(void* const* d_in, const int* in_sizes, int n_in,
                              void* d_out, int out_size, void* d_ws, size_t ws_size,
                              hipStream_t stream) {
    (void)in_sizes; (void)n_in; (void)out_size; (void)d_ws; (void)ws_size;
    const float* q = (const float*)d_in[0];
    const float* k = (const float*)d_in[1];
    const float* v = (const float*)d_in[2];
    // d_in[3] = mask: structural (causal sliding window, W=512) — never read.
    float* o = (float*)d_out;
    hipLaunchKernelGGL(swa_fwd, dim3(NWG), dim3(512), 0, stream, q, k, v, o);
}